// Round 6
// baseline (76.531 us; speedup 1.0000x reference)
//
#include <hip/hip_runtime.h>

// ReflexPolicy fused v6: o-split grid (1024 blocks), 2-o chunks double-buffered,
// issue-early/write-late staging (T14), ~30.6KB LDS -> 4 blocks/CU, atomicAdd merge.

#define TOBS 64
#define TACT 32
#define TLAT 25
#define TB   8192
#define BT   16
#define NCH  16         // chunks of 2 o's over this block's 32 o's
#define ATS  28         // At stride words (25 data + 3 pad), 16B-aligned rows
#define WTS  20         // W stride words (16 data + 4 pad)
#define HSTR 68

#define DPP_ADD(x, ctrl) \
  ((x) + __builtin_bit_cast(float, __builtin_amdgcn_update_dpp( \
      0, __builtin_bit_cast(int, (x)), (ctrl), 0xF, 0xF, true)))

__device__ __forceinline__ float halfwave_sum(float x) {
    x = DPP_ADD(x, 0xB1);   // xor1
    x = DPP_ADD(x, 0x4E);   // xor2
    x = DPP_ADD(x, 0x141);  // row_half_mirror == xor4
    x = DPP_ADD(x, 0x140);  // row_mirror      == xor8
    int y = __builtin_amdgcn_ds_swizzle(__builtin_bit_cast(int, x), 0x401F); // xor16
    return x + __builtin_bit_cast(float, y);
}

__device__ __forceinline__ float sigmoidf_(float x) {
    return 1.0f / (1.0f + __expf(-x));
}

__global__ __launch_bounds__(256, 2)
void reflex_fused(const float* __restrict__ obs,
                  const float* __restrict__ sw1, const float* __restrict__ sb1,
                  const float* __restrict__ sw2, const float* __restrict__ sb2,
                  const float* __restrict__ sw3, const float* __restrict__ sb3,
                  const float* __restrict__ rw1, const float* __restrict__ rb1,
                  const float* __restrict__ rw2, const float* __restrict__ rb2,
                  const float* __restrict__ am,  float* __restrict__ out)
{
    __shared__ __align__(16) float obs_s[BT * HSTR];
    __shared__ __align__(16) float lat_s[BT * 26];
    __shared__ __align__(16) union {
        struct { float h1[BT * HSTR]; float h2[BT * HSTR]; } p1;
        struct { float At[2][64 * ATS]; float W[2][64 * WTS]; } p2;
    } U;

    const int tid   = threadIdx.x;
    const int bid   = blockIdx.x;
    const int row0  = (bid >> 1) * BT;
    const int obase = (bid & 1) * 32;

    // ---------------- Phase 1: supervisor (weights from L2) ----------------
    {
        const int r = tid >> 4, f = tid & 15;
        *(float4*)&obs_s[r * HSTR + f * 4] =
            *(const float4*)&obs[(row0 + r) * TOBS + f * 4];
    }
    __syncthreads();

    {   // layer 1
        const int r = tid >> 4, j0 = (tid & 15) * 4;
        float4 acc = *(const float4*)&sb1[j0];
        #pragma unroll 8
        for (int k = 0; k < 64; ++k) {
            float x = obs_s[r * HSTR + k];
            const float4 w = *(const float4*)&sw1[k * 64 + j0];
            acc.x = fmaf(x, w.x, acc.x); acc.y = fmaf(x, w.y, acc.y);
            acc.z = fmaf(x, w.z, acc.z); acc.w = fmaf(x, w.w, acc.w);
        }
        *(float4*)&U.p1.h1[r * HSTR + j0] =
            make_float4(fmaxf(acc.x, 0.f), fmaxf(acc.y, 0.f),
                        fmaxf(acc.z, 0.f), fmaxf(acc.w, 0.f));
    }
    __syncthreads();

    {   // layer 2
        const int r = tid >> 4, j0 = (tid & 15) * 4;
        float4 acc = *(const float4*)&sb2[j0];
        #pragma unroll 8
        for (int k = 0; k < 64; ++k) {
            float x = U.p1.h1[r * HSTR + k];
            const float4 w = *(const float4*)&sw2[k * 64 + j0];
            acc.x = fmaf(x, w.x, acc.x); acc.y = fmaf(x, w.y, acc.y);
            acc.z = fmaf(x, w.z, acc.z); acc.w = fmaf(x, w.w, acc.w);
        }
        *(float4*)&U.p1.h2[r * HSTR + j0] =
            make_float4(fmaxf(acc.x, 0.f), fmaxf(acc.y, 0.f),
                        fmaxf(acc.z, 0.f), fmaxf(acc.w, 0.f));
    }
    __syncthreads();

    {   // layer 3 -> lat_s
        const int r = tid >> 4, q = tid & 15;
        if (q < 13) {
            const int j = q * 2;
            float a0 = sb3[j];
            float a1 = (j + 1 < TLAT) ? sb3[j + 1] : 0.f;
            #pragma unroll 8
            for (int k = 0; k < 64; ++k) {
                float x = U.p1.h2[r * HSTR + k];
                a0 = fmaf(x, sw3[k * TLAT + j], a0);
                if (j + 1 < TLAT) a1 = fmaf(x, sw3[k * TLAT + j + 1], a1);
            }
            lat_s[r * 26 + j] = sigmoidf_(a0);
            if (j + 1 < TLAT) lat_s[r * 26 + j + 1] = sigmoidf_(a1);
        }
    }
    __syncthreads();   // lat_s ready; h1/h2 (union) dead after this point

    // ---------------- Phase 2 ----------------
    const int a  = tid & 31;
    const int hw = tid >> 5;
    const int r0 = hw * 2, r1 = r0 + 1;

    float latA[TLAT], latB[TLAT];
    #pragma unroll
    for (int l = 0; l < TLAT; ++l) {
        latA[l] = lat_s[r0 * 26 + l];
        latB[l] = lat_s[r1 * 26 + l];
    }

    // Staging roles (64 threads each): 0: At l=0..11, 1: At l=12..24,
    // 2: W words 0..7 (w1[0..4],b1[0..2]), 3: W words 8..15 (b1[3..4],w2[0..4],b2)
    const int role = tid >> 6;
    const int rt   = tid & 63;          // index within role: slot*32 + a
    const int rslot = rt >> 5, ra = rt & 31;
    float s0, s1, s2, s3, s4, s5, s6, s7, s8, s9, s10, s11, s12;

    auto stage_load = [&](int c) {
        const int o = obase + c * 2 + rslot;
        if (role == 0) {
            const float* g = am + o * TACT + ra;
            s0 = g[0*2048];  s1 = g[1*2048];  s2  = g[2*2048];  s3  = g[3*2048];
            s4 = g[4*2048];  s5 = g[5*2048];  s6  = g[6*2048];  s7  = g[7*2048];
            s8 = g[8*2048];  s9 = g[9*2048];  s10 = g[10*2048]; s11 = g[11*2048];
        } else if (role == 1) {
            const float* g = am + o * TACT + ra;
            s0 = g[12*2048]; s1 = g[13*2048]; s2  = g[14*2048]; s3  = g[15*2048];
            s4 = g[16*2048]; s5 = g[17*2048]; s6  = g[18*2048]; s7  = g[19*2048];
            s8 = g[20*2048]; s9 = g[21*2048]; s10 = g[22*2048]; s11 = g[23*2048];
            s12 = g[24*2048];
        } else if (role == 2) {
            const int gb = (o * TACT + ra) * 5;
            s0 = rw1[gb]; s1 = rw1[gb+1]; s2 = rw1[gb+2]; s3 = rw1[gb+3];
            s4 = rw1[gb+4]; s5 = rb1[gb]; s6 = rb1[gb+1]; s7 = rb1[gb+2];
        } else {
            const int gb = (o * TACT + ra) * 5;
            s0 = rb1[gb+3]; s1 = rb1[gb+4]; s2 = rw2[gb]; s3 = rw2[gb+1];
            s4 = rw2[gb+2]; s5 = rw2[gb+3]; s6 = rw2[gb+4]; s7 = rb2[o * TACT + ra];
        }
    };

    auto stage_write = [&](int b) {
        if (role == 0) {
            float* d = &U.p2.At[b][rt * ATS];
            ((float4*)d)[0] = make_float4(s0, s1, s2,  s3);
            ((float4*)d)[1] = make_float4(s4, s5, s6,  s7);
            ((float4*)d)[2] = make_float4(s8, s9, s10, s11);
        } else if (role == 1) {
            float* d = &U.p2.At[b][rt * ATS];
            ((float4*)d)[3] = make_float4(s0, s1, s2,  s3);
            ((float4*)d)[4] = make_float4(s4, s5, s6,  s7);
            ((float4*)d)[5] = make_float4(s8, s9, s10, s11);
            d[24] = s12;
        } else if (role == 2) {
            float* d = &U.p2.W[b][rt * WTS];
            ((float4*)d)[0] = make_float4(s0, s1, s2, s3);
            ((float4*)d)[1] = make_float4(s4, s5, s6, s7);
        } else {
            float* d = &U.p2.W[b][rt * WTS];
            ((float4*)d)[2] = make_float4(s0, s1, s2, s3);
            ((float4*)d)[3] = make_float4(s4, s5, s6, s7);
        }
    };

    float acc0 = 0.f, acc1 = 0.f;

    stage_load(0);
    stage_write(0);
    __syncthreads();

    for (int c = 0; c < NCH; ++c) {
        if (c + 1 < NCH) stage_load(c + 1);     // issue-early: latency hides under compute

        const float* Atb = U.p2.At[c & 1];
        const float* Wb  = U.p2.W[c & 1];
        #pragma unroll
        for (int i = 0; i < 2; ++i) {
            const int o  = obase + c * 2 + i;
            const float* Ap = &Atb[(i * 32 + a) * ATS];
            const float4 A0 = ((const float4*)Ap)[0];
            const float4 A1 = ((const float4*)Ap)[1];
            const float4 A2 = ((const float4*)Ap)[2];
            const float4 A3 = ((const float4*)Ap)[3];
            const float4 A4 = ((const float4*)Ap)[4];
            const float4 A5 = ((const float4*)Ap)[5];
            const float  a24 = Ap[24];

            float l0 = 0.f, l1 = 0.f;
            #define DOT_(comp, idx) \
                l0 = fmaf((comp), latA[idx], l0); l1 = fmaf((comp), latB[idx], l1);
            DOT_(A0.x, 0)  DOT_(A0.y, 1)  DOT_(A0.z, 2)  DOT_(A0.w, 3)
            DOT_(A1.x, 4)  DOT_(A1.y, 5)  DOT_(A1.z, 6)  DOT_(A1.w, 7)
            DOT_(A2.x, 8)  DOT_(A2.y, 9)  DOT_(A2.z, 10) DOT_(A2.w, 11)
            DOT_(A3.x, 12) DOT_(A3.y, 13) DOT_(A3.z, 14) DOT_(A3.w, 15)
            DOT_(A4.x, 16) DOT_(A4.y, 17) DOT_(A4.z, 18) DOT_(A4.w, 19)
            DOT_(A5.x, 20) DOT_(A5.y, 21) DOT_(A5.z, 22) DOT_(A5.w, 23)
            DOT_(a24, 24)
            #undef DOT_

            float e0 = __expf(l0), e1 = __expf(l1);
            float p0 = e0 * __builtin_amdgcn_rcpf(halfwave_sum(e0));
            float p1 = e1 * __builtin_amdgcn_rcpf(halfwave_sum(e1));

            const float* Wp = &Wb[(i * 32 + a) * WTS];
            const float4 W0 = ((const float4*)Wp)[0];
            const float4 W1 = ((const float4*)Wp)[1];
            const float4 W2 = ((const float4*)Wp)[2];
            const float4 W3 = ((const float4*)Wp)[3];

            float x0 = obs_s[r0 * HSTR + o], x1 = obs_s[r1 * HSTR + o];
            float ro0 = W3.w, ro1 = W3.w;
            // w1 = {W0.x..W0.w,W1.x}, b1 = {W1.y..W1.w,W2.x,W2.y},
            // w2 = {W2.z,W2.w,W3.x,W3.y,W3.z}, b2 = W3.w
            ro0 = fmaf(fmaxf(fmaf(x0, W0.x, W1.y), 0.f), W2.z, ro0);
            ro1 = fmaf(fmaxf(fmaf(x1, W0.x, W1.y), 0.f), W2.z, ro1);
            ro0 = fmaf(fmaxf(fmaf(x0, W0.y, W1.z), 0.f), W2.w, ro0);
            ro1 = fmaf(fmaxf(fmaf(x1, W0.y, W1.z), 0.f), W2.w, ro1);
            ro0 = fmaf(fmaxf(fmaf(x0, W0.z, W1.w), 0.f), W3.x, ro0);
            ro1 = fmaf(fmaxf(fmaf(x1, W0.z, W1.w), 0.f), W3.x, ro1);
            ro0 = fmaf(fmaxf(fmaf(x0, W0.w, W2.x), 0.f), W3.y, ro0);
            ro1 = fmaf(fmaxf(fmaf(x1, W0.w, W2.x), 0.f), W3.y, ro1);
            ro0 = fmaf(fmaxf(fmaf(x0, W1.x, W2.y), 0.f), W3.z, ro0);
            ro1 = fmaf(fmaxf(fmaf(x1, W1.x, W2.y), 0.f), W3.z, ro1);

            acc0 = fmaf(ro0, p0, acc0);
            acc1 = fmaf(ro1, p1, acc1);
        }

        if (c + 1 < NCH) stage_write((c + 1) & 1);   // write-late into idle buffer
        __syncthreads();
    }

    // merge the two o-half blocks (2 commutative fp32 adds -> deterministic)
    unsafeAtomicAdd(&out[(row0 + r0) * TACT + a], acc0);
    unsafeAtomicAdd(&out[(row0 + r1) * TACT + a], acc1);
}

extern "C" void kernel_launch(void* const* d_in, const int* in_sizes, int n_in,
                              void* d_out, int out_size, void* d_ws, size_t ws_size,
                              hipStream_t stream) {
    const float* obs = (const float*)d_in[0];
    const float* sw1 = (const float*)d_in[1];
    const float* sb1 = (const float*)d_in[2];
    const float* sw2 = (const float*)d_in[3];
    const float* sb2 = (const float*)d_in[4];
    const float* sw3 = (const float*)d_in[5];
    const float* sb3 = (const float*)d_in[6];
    const float* rw1 = (const float*)d_in[7];
    const float* rb1 = (const float*)d_in[8];
    const float* rw2 = (const float*)d_in[9];
    const float* rb2 = (const float*)d_in[10];
    const float* am  = (const float*)d_in[11];
    float* out = (float*)d_out;

    hipMemsetAsync(out, 0, (size_t)out_size * sizeof(float), stream);
    reflex_fused<<<(TB / BT) * 2, 256, 0, stream>>>(obs, sw1, sb1, sw2, sb2, sw3, sb3,
                                                    rw1, rb1, rw2, rb2, am, out);
}